// Round 6
// baseline (173.111 us; speedup 1.0000x reference)
//
#include <hip/hip_runtime.h>
#include <math.h>

#define N_ 8192
#define D_ 512
#define NC_ 128
#define T_ 64   // 8192/128 row-tiles

typedef __attribute__((ext_vector_type(8))) short bf16x8;
typedef __attribute__((ext_vector_type(4))) float f32x4;
typedef __attribute__((ext_vector_type(4))) unsigned short us4;

static __device__ __forceinline__ unsigned short f2bf(float f) {
    union { float f; unsigned u; } c; c.f = f;
    unsigned u = c.u;
    u += 0x7fffu + ((u >> 16) & 1u);   // round-to-nearest-even
    return (unsigned short)(u >> 16);
}

// ---------- kernel 1: fused prep ----------
// blocks [0,4096): fp32->bf16 convert
// blocks [4096,6144): exact fp64 last-row dots -> sim_last
// block 6144: class histogram + zero control words
__global__ __launch_bounds__(256) void k_prep(const float* __restrict__ x,
                                              const int* __restrict__ tg,
                                              unsigned short* __restrict__ xb,
                                              double* __restrict__ sim_last,
                                              int* __restrict__ hist,
                                              int* __restrict__ done,
                                              int* __restrict__ skipAcc,
                                              double* __restrict__ lossAcc) {
    const int b = blockIdx.x;
    if (b < 4096) {
        int i = b * 256 + threadIdx.x;
        float4 v = reinterpret_cast<const float4*>(x)[i];
        us4 o = { f2bf(v.x), f2bf(v.y), f2bf(v.z), f2bf(v.w) };
        reinterpret_cast<us4*>(xb)[i] = o;
    } else if (b < 6144) {
        int j    = ((b - 4096) * 256 + threadIdx.x) >> 6;
        int lane = threadIdx.x & 63;
        const float* xl = x + (size_t)(N_ - 1) * D_;
        const float* xj = x + (size_t)j * D_;
        double acc = 0.0;
#pragma unroll
        for (int it = 0; it < 8; ++it) {
            int k = it * 64 + lane;
            acc += (double)xl[k] * (double)xj[k];
        }
#pragma unroll
        for (int m = 32; m >= 1; m >>= 1) acc += __shfl_xor(acc, m, 64);
        if (lane == 0) sim_last[j] = acc;
    } else {
        __shared__ int lh[NC_];
        if (threadIdx.x < NC_) lh[threadIdx.x] = 0;
        if (threadIdx.x == 0) { *done = 0; *skipAcc = 0; *lossAcc = 0.0; }
        __syncthreads();
        for (int i = threadIdx.x; i < N_; i += 256) atomicAdd(&lh[tg[i]], 1);
        __syncthreads();
        if (threadIdx.x < NC_) hist[threadIdx.x] = lh[threadIdx.x];
    }
}

// ---------- kernel 2: symmetric fused MFMA sim + masked exp partials ----------
// (identical to R5 — 512 threads, 128x256 tile, packed no-atomic partials)
__global__ __launch_bounds__(512, 4) void k_main(const unsigned short* __restrict__ xb,
                                                 const int* __restrict__ tg,
                                                 float* __restrict__ bufP,
                                                 float* __restrict__ bufN) {
    __shared__ alignas(16) unsigned short As[128 * 64];   // 16 KB
    __shared__ alignas(16) unsigned short Bs[256 * 64];   // 32 KB
    __shared__ int rowT[128];

    const int tid  = threadIdx.x;
    const int w    = tid >> 6;       // 0..7
    const int lane = tid & 63;
    const int q    = lane >> 4;
    const int l15  = lane & 15;
    const int wrow = w >> 2;         // 0..1
    const int wcol = w & 3;          // 0..3

    int rem = blockIdx.x;
    int it = 0;
    while (rem >= 32 - (it >> 1)) { rem -= 32 - (it >> 1); it++; }
    const int jt2  = (it >> 1) + rem;
    const int row0 = it * 128;
    const int col0 = jt2 * 256;

    const int bsub   = 2 * jt2 + (wcol >> 1);
    const bool rowOK = (bsub >= it);

    if (tid < 128) rowT[tid] = tg[row0 + tid];
    __syncthreads();

    int tR[4][4];
#pragma unroll
    for (int mi = 0; mi < 4; ++mi)
#pragma unroll
        for (int r = 0; r < 4; ++r)
            tR[mi][r] = rowT[wrow * 64 + mi * 16 + q * 4 + r];

    int tC[4];
#pragma unroll
    for (int ni = 0; ni < 4; ++ni)
        tC[ni] = tg[col0 + wcol * 64 + ni * 16 + l15];

    f32x4 acc[4][4];
#pragma unroll
    for (int mi = 0; mi < 4; ++mi)
#pragma unroll
        for (int ni = 0; ni < 4; ++ni)
            acc[mi][ni] = (f32x4){0.f, 0.f, 0.f, 0.f};

    for (int ks = 0; ks < 8; ++ks) {
        const int k0 = ks * 64;
        __syncthreads();
#pragma unroll
        for (int i2 = 0; i2 < 2; ++i2) {
            int slot = i2 * 512 + tid;
            int r  = slot >> 3;
            int s  = slot & 7;
            int g  = s ^ (r & 7);
            const unsigned short* ga = xb + (size_t)(row0 + r) * D_ + k0 + g * 8;
            __builtin_amdgcn_global_load_lds(
                (const __attribute__((address_space(1))) void*)ga,
                (__attribute__((address_space(3))) void*)(As + (i2 * 512 + w * 64) * 8),
                16, 0, 0);
        }
#pragma unroll
        for (int i2 = 0; i2 < 4; ++i2) {
            int slot = i2 * 512 + tid;
            int r  = slot >> 3;
            int s  = slot & 7;
            int g  = s ^ (r & 7);
            const unsigned short* gb = xb + (size_t)(col0 + r) * D_ + k0 + g * 8;
            __builtin_amdgcn_global_load_lds(
                (const __attribute__((address_space(1))) void*)gb,
                (__attribute__((address_space(3))) void*)(Bs + (i2 * 512 + w * 64) * 8),
                16, 0, 0);
        }
        __syncthreads();

#pragma unroll
        for (int kc = 0; kc < 2; ++kc) {
            bf16x8 aF[4], bF[4];
#pragma unroll
            for (int mi = 0; mi < 4; ++mi) {
                int rA = wrow * 64 + mi * 16 + l15;
                int g  = kc * 4 + q;
                int s  = g ^ (rA & 7);
                aF[mi] = *reinterpret_cast<const bf16x8*>(As + rA * 64 + s * 8);
            }
#pragma unroll
            for (int ni = 0; ni < 4; ++ni) {
                int rB = wcol * 64 + ni * 16 + l15;
                int g  = kc * 4 + q;
                int s  = g ^ (rB & 7);
                bF[ni] = *reinterpret_cast<const bf16x8*>(Bs + rB * 64 + s * 8);
            }
#pragma unroll
            for (int mi = 0; mi < 4; ++mi)
#pragma unroll
                for (int ni = 0; ni < 4; ++ni)
                    acc[mi][ni] = __builtin_amdgcn_mfma_f32_16x16x32_bf16(
                        aF[mi], bF[ni], acc[mi][ni], 0, 0, 0);
        }
    }

    float ps[4][4], ns[4][4];
    float cps[4], cns[4];
#pragma unroll
    for (int mi = 0; mi < 4; ++mi)
#pragma unroll
        for (int r = 0; r < 4; ++r) { ps[mi][r] = 0.f; ns[mi][r] = 0.f; }
#pragma unroll
    for (int ni = 0; ni < 4; ++ni) { cps[ni] = 0.f; cns[ni] = 0.f; }

    if (rowOK) {
#pragma unroll
        for (int mi = 0; mi < 4; ++mi)
#pragma unroll
            for (int ni = 0; ni < 4; ++ni)
#pragma unroll
                for (int r = 0; r < 4; ++r) {
                    float s = acc[mi][ni][r];
                    bool same = (tR[mi][r] == tC[ni]);
                    float e = __expf(same ? 1.0f - s : s);
                    float pe = (same && (s < 1.0f)) ? e : 0.0f;
                    float ne = same ? 0.0f : e;
                    ps[mi][r] += pe; ns[mi][r] += ne;
                    cps[ni]   += pe; cns[ni]   += ne;
                }
    }

    __syncthreads();
    float* scr = (float*)As;

#pragma unroll
    for (int mi = 0; mi < 4; ++mi)
#pragma unroll
        for (int r = 0; r < 4; ++r) {
            float p = ps[mi][r];
            float n = ns[mi][r];
#pragma unroll
            for (int m = 1; m < 16; m <<= 1) {
                p += __shfl_xor(p, m, 64);
                n += __shfl_xor(n, m, 64);
            }
            if (l15 == 0) {
                int rloc = wrow * 64 + mi * 16 + q * 4 + r;
                scr[wcol * 128 + rloc]       = p;
                scr[512 + wcol * 128 + rloc] = n;
            }
        }

#pragma unroll
    for (int ni = 0; ni < 4; ++ni) {
        float p = cps[ni];
        float n = cns[ni];
        p += __shfl_xor(p, 16, 64); p += __shfl_xor(p, 32, 64);
        n += __shfl_xor(n, 16, 64); n += __shfl_xor(n, 32, 64);
        if (q == 0) {
            int cloc = wcol * 64 + ni * 16 + l15;
            scr[1024 + wrow * 256 + cloc] = p;
            scr[1536 + wrow * 256 + cloc] = n;
        }
    }
    __syncthreads();

    if (tid < 128) {
        int r = tid;
        int s_row = it + jt2 - (it >> 1);
        size_t off = ((size_t)it * T_ + s_row) * 128 + r;
        bufP[off] = scr[r] + scr[128 + r] + scr[256 + r] + scr[384 + r];
        bufN[off] = scr[512 + r] + scr[640 + r] + scr[768 + r] + scr[896 + r];
    } else if (tid < 384) {
        int c  = tid - 128;
        int bc = 2 * jt2 + (c >> 7);
        if (bc > it) {
            size_t off = ((size_t)bc * T_ + it) * 128 + (c & 127);
            bufP[off] = scr[1024 + c] + scr[1280 + c];
            bufN[off] = scr[1536 + c] + scr[1792 + c];
        }
    }
}

// ---------- kernel 3: reduce + finalize (last-block election) ----------
// 64 blocks x 256 threads. Block t sums its tile's packed partials, computes
// row losses locally, contributes via device-scope atomics; last block to
// arrive computes sim_last stats and writes the 4 outputs.
__global__ __launch_bounds__(256) void k_tail(const float* __restrict__ bufP,
                                              const float* __restrict__ bufN,
                                              const int* __restrict__ tg,
                                              const int* __restrict__ hist,
                                              const double* __restrict__ sim_last,
                                              int* __restrict__ done,
                                              int* __restrict__ skipAcc,
                                              double* __restrict__ lossAcc,
                                              float* __restrict__ out) {
    __shared__ float  pn[256];
    __shared__ double sdA[256], sdB[256];
    __shared__ int    siA[256], siB[256];
    __shared__ int    amLast;

    const int tid  = threadIdx.x;
    const int t    = blockIdx.x;
    const int half = tid >> 7;
    const int r    = tid & 127;
    const int smax = t + 32 - (t >> 1);

    const float* buf  = half ? bufN : bufP;
    const float* base = buf + (size_t)t * T_ * 128 + r;
    float s = 0.f;
    for (int o = 0; o < smax; ++o) s += base[o * 128];
    pn[tid] = s;
    __syncthreads();

    // threads 0..127: per-row loss
    double part = 0.0;
    int skip = 0;
    if (half == 0) {
        int gi = t * 128 + r;
        if (hist[tg[gi]] < N_) part = (double)(logf(pn[r]) + logf(pn[128 + r]));
        else skip = 1;
    }
    sdA[tid] = part; siA[tid] = skip;
    __syncthreads();
    for (int st = 128; st >= 1; st >>= 1) {
        if (tid < st) { sdA[tid] += sdA[tid + st]; siA[tid] += siA[tid + st]; }
        __syncthreads();
    }

    if (tid == 0) {
        atomicAdd(lossAcc, sdA[0]);
        atomicAdd(skipAcc, siA[0]);
        __threadfence();                       // release before arrival
        amLast = (atomicAdd(done, 1) == T_ - 1);
    }
    __syncthreads();
    if (!amLast) return;

    // elected block: final scalars
    __shared__ double finLoss;
    __shared__ int    finSkip;
    if (tid == 0) {
        __threadfence();                       // acquire
        finLoss = atomicAdd(lossAcc, 0.0);     // coherent read incl. own add
        finSkip = atomicAdd(skipAcc, 0);
    }

    double pd = 0.0, nd = 0.0;
    int pc = 0, nc = 0;
    int tlast = tg[N_ - 1];
    for (int j = tid; j < N_; j += 256) {
        double sv = sim_last[j];
        if (tg[j] == tlast) {
            if (sv < 1.0) { pd += sv; pc++; }
        } else {
            nd += sv; nc++;
        }
    }
    sdA[tid] = pd; sdB[tid] = nd; siA[tid] = pc; siB[tid] = nc;
    __syncthreads();
    for (int st = 128; st >= 1; st >>= 1) {
        if (tid < st) {
            sdA[tid] += sdA[tid + st]; sdB[tid] += sdB[tid + st];
            siA[tid] += siA[tid + st]; siB[tid] += siB[tid + st];
        }
        __syncthreads();
    }
    if (tid == 0) {
        out[0] = (float)(finLoss / (double)N_);
        out[1] = (float)finSkip / (float)N_;
        out[2] = (float)(sdA[0] / (double)siA[0]);
        out[3] = (float)(sdB[0] / (double)siB[0]);
    }
}

extern "C" void kernel_launch(void* const* d_in, const int* in_sizes, int n_in,
                              void* d_out, int out_size, void* d_ws, size_t ws_size,
                              hipStream_t stream) {
    const float* x  = (const float*)d_in[0];
    const int*   tg = (const int*)d_in[1];
    char* ws = (char*)d_ws;

    unsigned short* xb = (unsigned short*)ws;                 // 8 MB
    const size_t XB = (size_t)N_ * D_ * 2;                    // 8388608
    double* sim_last = (double*)(ws + XB);                    // 64 KB
    float*  bufP     = (float*)(ws + XB + 65536);             // 2 MB
    float*  bufN     = (float*)(ws + XB + 65536 + 2097152);   // 2 MB
    char*   ctrl     = ws + XB + 65536 + 2 * 2097152;
    int*    hist     = (int*)ctrl;                            // 512 B
    int*    done     = (int*)(ctrl + 512);
    int*    skipAcc  = (int*)(ctrl + 516);
    double* lossAcc  = (double*)(ctrl + 520);

    const int nblk = 1056;   // sum over it of (32 - it/2)

    hipLaunchKernelGGL(k_prep, dim3(4096 + 2048 + 1), dim3(256), 0, stream,
                       x, tg, xb, sim_last, hist, done, skipAcc, lossAcc);
    hipLaunchKernelGGL(k_main, dim3(nblk), dim3(512), 0, stream, xb, tg, bufP, bufN);
    hipLaunchKernelGGL(k_tail, dim3(T_), dim3(256), 0, stream,
                       bufP, bufN, tg, hist, sim_last, done, skipAcc, lossAcc,
                       (float*)d_out);
}